// Round 1
// baseline (649.297 us; speedup 1.0000x reference)
//
#include <hip/hip_runtime.h>
#include <cstdint>
#include <cstddef>

typedef __bf16 bf16_t;
typedef bf16_t bf16x8 __attribute__((ext_vector_type(8)));
typedef float floatx4 __attribute__((ext_vector_type(4)));

#define B_   128
#define T_   64
#define H_   512
#define IN_  2048
#define FS_  1536
#define M_   (B_ * T_)   // 8192

// ---------------------------------------------------------------------------
// async global->LDS, 16B per lane. LDS dest is wave-uniform base + lane*16.
// ---------------------------------------------------------------------------
__device__ __forceinline__ void async16(void* lds, const void* gp) {
  __builtin_amdgcn_global_load_lds(
      (const __attribute__((address_space(1))) void*)gp,
      (__attribute__((address_space(3))) void*)lds, 16, 0, 0);
}

// ---------------------------------------------------------------------------
// fp32 -> bf16 conversion, 8 elems/thread (all sizes divisible by 2048)
// ---------------------------------------------------------------------------
__global__ __launch_bounds__(256) void cvt_bf16_k(const float* __restrict__ s,
                                                  bf16_t* __restrict__ d, int n8) {
  int i = blockIdx.x * 256 + threadIdx.x;
  if (i >= n8) return;
  const float4* s4 = (const float4*)s;
  float4 v0 = s4[2 * (size_t)i];
  float4 v1 = s4[2 * (size_t)i + 1];
  bf16x8 o;
  o[0] = (bf16_t)v0.x; o[1] = (bf16_t)v0.y; o[2] = (bf16_t)v0.z; o[3] = (bf16_t)v0.w;
  o[4] = (bf16_t)v1.x; o[5] = (bf16_t)v1.y; o[6] = (bf16_t)v1.z; o[7] = (bf16_t)v1.w;
  *(bf16x8*)(d + (size_t)i * 8) = o;
}

// ---------------------------------------------------------------------------
// C[M,N] = A[M,K] * B[N,K]^T + bias[N]   (bf16 in, fp32 out)
// m97 structure: 128x128 tile, BK=32, 256 thr (4 waves, 2x2), 16x16x32 MFMA.
// M,N,K all divide tile dims exactly for our shapes -> no bounds checks.
// ---------------------------------------------------------------------------
#define BM 128
#define BN 128
#define BK 32

__global__ __launch_bounds__(256) void gemm_bt_bias(
    const bf16_t* __restrict__ A, const bf16_t* __restrict__ B,
    const float* __restrict__ bias, float* __restrict__ C,
    int M, int N, int K) {
  __shared__ __align__(16) bf16_t As[BM * BK];
  __shared__ __align__(16) bf16_t Bs[BN * BK];

  const int tid  = threadIdx.x;
  const int lane = tid & 63;
  const int wave = tid >> 6;
  const int wr = wave >> 1, wc = wave & 1;
  const int mblk = blockIdx.y * BM;
  const int nblk = blockIdx.x * BN;

  // staging: wave w handles chunks (2w, 2w+1); chunk = 16 rows x 32 k = 1024B
  const int sr = lane >> 2;           // row within chunk
  const int sc = (lane & 3) * 8;      // k elem offset
  const int c0 = wave * 2;

  const bf16_t* Ag0 = A + (size_t)(mblk + c0 * 16 + sr) * K + sc;
  const bf16_t* Ag1 = A + (size_t)(mblk + c0 * 16 + 16 + sr) * K + sc;
  const bf16_t* Bg0 = B + (size_t)(nblk + c0 * 16 + sr) * K + sc;
  const bf16_t* Bg1 = B + (size_t)(nblk + c0 * 16 + 16 + sr) * K + sc;
  bf16_t* As0 = As + c0 * 512;
  bf16_t* Bs0 = Bs + c0 * 512;

  floatx4 acc[4][4] = {};

  const int fm = lane & 15;           // 16-dim index within fragment
  const int fk = (lane >> 4) * 8;     // k offset within fragment

  for (int kt = 0; kt < K; kt += BK) {
    async16(As0,       Ag0 + kt);
    async16(As0 + 512, Ag1 + kt);
    async16(Bs0,       Bg0 + kt);
    async16(Bs0 + 512, Bg1 + kt);
    __syncthreads();   // compiler drains vmcnt before s_barrier

    bf16x8 a[4], b[4];
#pragma unroll
    for (int i = 0; i < 4; i++)
      a[i] = *(const bf16x8*)(As + (wr * 64 + i * 16 + fm) * BK + fk);
#pragma unroll
    for (int j = 0; j < 4; j++)
      b[j] = *(const bf16x8*)(Bs + (wc * 64 + j * 16 + fm) * BK + fk);
#pragma unroll
    for (int i = 0; i < 4; i++)
#pragma unroll
      for (int j = 0; j < 4; j++)
        acc[i][j] = __builtin_amdgcn_mfma_f32_16x16x32_bf16(a[i], b[j], acc[i][j], 0, 0, 0);
    __syncthreads();
  }

  // epilogue: C/D layout col=lane&15 (n), row=quad*4+reg (m)
  const int en  = nblk + wc * 64 + (lane & 15);
  const int em0 = mblk + wr * 64 + (lane >> 4) * 4;
#pragma unroll
  for (int j = 0; j < 4; j++) {
    int col = en + j * 16;
    float bv = bias[col];
#pragma unroll
    for (int i = 0; i < 4; i++) {
#pragma unroll
      for (int r = 0; r < 4; r++) {
        int row = em0 + i * 16 + r;
        C[(size_t)row * N + col] = acc[i][r < 4 ? j : j][r] + bv;  // acc[i][j][r]
      }
    }
  }
}

// ---------------------------------------------------------------------------
// One GRU step. 256 blocks x 64 threads. Block (mb,nb): 16 batch rows x
// 16 hidden cols, all 3 gates. gh = h_bf16 @ Whh^T, K=512.
// Fragments read directly from global (L2-resident): each b128 instruction
// touches 16 full 64B lines. h is ping-pong buffered across steps.
// ---------------------------------------------------------------------------
__global__ __launch_bounds__(64) void gru_step(
    const bf16_t* __restrict__ hb_in, const float* __restrict__ hf_in,
    bf16_t* __restrict__ hb_out, float* __restrict__ hf_out,
    const bf16_t* __restrict__ Whh,   // [3H][H] bf16
    const float* __restrict__ bhh,    // [3H]
    const float* __restrict__ gi,     // [M][3H] fp32
    const float* __restrict__ gf,     // [M][2H] fp32
    float* __restrict__ eo,           // [B][T][H] fp32 (d_out)
    int t) {
  const int lane = threadIdx.x;
  const int mb = blockIdx.x >> 5;     // 0..7   (batch tiles of 16)
  const int nb = blockIdx.x & 31;     // 0..31  (hidden-col tiles of 16)
  const int m0 = mb * 16;
  const int n0 = nb * 16;
  const int lm = lane & 15;
  const int lq = lane >> 4;

  // A fragments: h rows m0+lm, k = lq*8 + kt*32
  const bf16_t* aRow = hb_in + (size_t)(m0 + lm) * H_ + lq * 8;
  bf16x8 a[16];
#pragma unroll
  for (int kt = 0; kt < 16; kt++) a[kt] = *(const bf16x8*)(aRow + kt * 32);

  floatx4 acc[3] = {};
#pragma unroll
  for (int g = 0; g < 3; g++) {
    const bf16_t* bRow = Whh + ((size_t)g * H_ + n0 + lm) * H_ + lq * 8;
#pragma unroll
    for (int kt = 0; kt < 16; kt++) {
      bf16x8 b = *(const bf16x8*)(bRow + kt * 32);
      acc[g] = __builtin_amdgcn_mfma_f32_16x16x32_bf16(a[kt], b, acc[g], 0, 0, 0);
    }
  }

  const int col = n0 + lm;
  const float b0 = bhh[col];
  const float b1 = bhh[H_ + col];
  const float b2 = bhh[2 * H_ + col];
#pragma unroll
  for (int r = 0; r < 4; r++) {
    const int brow = m0 + lq * 4 + r;             // batch index
    const size_t mrow = (size_t)brow * T_ + t;    // row into gi/gf/eo
    float ir = gi[mrow * (3 * H_) + col];
    float ii = gi[mrow * (3 * H_) + H_ + col];
    float in_ = gi[mrow * (3 * H_) + 2 * H_ + col];
    float fr = gf[mrow * (2 * H_) + col];
    float fi = gf[mrow * (2 * H_) + H_ + col];
    float hp = hf_in[(size_t)brow * H_ + col];

    float hr = acc[0][r] + b0;
    float hi = acc[1][r] + b1;
    float hn = acc[2][r] + b2;
    float rg = 1.f / (1.f + __expf(-(ir + hr + fr)));
    float ig = 1.f / (1.f + __expf(-(ii + hi + fi)));
    float ng = tanhf(in_ + rg * hn);
    float hy = ng + ig * (hp - ng);

    eo[mrow * H_ + col] = hy;
    hf_out[(size_t)brow * H_ + col] = hy;
    hb_out[(size_t)brow * H_ + col] = (bf16_t)hy;
  }
}

// ---------------------------------------------------------------------------
extern "C" void kernel_launch(void* const* d_in, const int* in_sizes, int n_in,
                              void* d_out, int out_size, void* d_ws, size_t ws_size,
                              hipStream_t stream) {
  const float* feat0 = (const float*)d_in[0];  // [B,T,FS]
  const float* feat1 = (const float*)d_in[1];  // [B,T,IN]
  const float* W_ih  = (const float*)d_in[2];  // [3H,IN]
  const float* b_ih  = (const float*)d_in[3];
  const float* W_hh  = (const float*)d_in[4];  // [3H,H]
  const float* b_hh  = (const float*)d_in[5];
  const float* W_fh  = (const float*)d_in[6];  // [2H,FS]
  const float* b_fh  = (const float*)d_in[7];
  float* out = (float*)d_out;                  // eo [B,T,H] ++ hT [B,H]

  char* p = (char*)d_ws;
  float*  h0f  = (float*)p;  p += (size_t)B_ * H_ * 4;   // 256 KB
  bf16_t* h0b  = (bf16_t*)p; p += (size_t)B_ * H_ * 2;   // 128 KB  (memset with h0f)
  float*  h1f  = (float*)p;  p += (size_t)B_ * H_ * 4;
  bf16_t* h1b  = (bf16_t*)p; p += (size_t)B_ * H_ * 2;
  float*  gi   = (float*)p;  p += (size_t)M_ * 3 * H_ * 4;   // 48 MB
  float*  gf   = (float*)p;  p += (size_t)M_ * 2 * H_ * 4;   // 32 MB
  bf16_t* A1   = (bf16_t*)p; p += (size_t)M_ * IN_ * 2;      // 32 MB
  bf16_t* A0   = (bf16_t*)p; p += (size_t)M_ * FS_ * 2;      // 24 MB
  bf16_t* Wihb = (bf16_t*)p; p += (size_t)3 * H_ * IN_ * 2;  // 6 MB
  bf16_t* Wfhb = (bf16_t*)p; p += (size_t)2 * H_ * FS_ * 2;  // 3 MB
  bf16_t* Whhb = (bf16_t*)p; p += (size_t)3 * H_ * H_ * 2;   // 1.5 MB

  // zero initial hidden state (fp32 + bf16 copies are adjacent)
  hipMemsetAsync(h0f, 0, (size_t)B_ * H_ * 4 + (size_t)B_ * H_ * 2, stream);

  // fp32 -> bf16 conversions
  auto cvt = [&](const float* s, bf16_t* d, size_t n) {
    int n8 = (int)(n / 8);
    cvt_bf16_k<<<(n8 + 255) / 256, 256, 0, stream>>>(s, d, n8);
  };
  cvt(feat1, A1, (size_t)M_ * IN_);
  cvt(feat0, A0, (size_t)M_ * FS_);
  cvt(W_ih, Wihb, (size_t)3 * H_ * IN_);
  cvt(W_fh, Wfhb, (size_t)2 * H_ * FS_);
  cvt(W_hh, Whhb, (size_t)3 * H_ * H_);

  // gi = feat1 @ W_ih^T + b_ih   : M=8192 N=1536 K=2048
  gemm_bt_bias<<<dim3((3 * H_) / BN, M_ / BM), 256, 0, stream>>>(
      A1, Wihb, b_ih, gi, M_, 3 * H_, IN_);
  // gf = feat0 @ W_fh^T + b_fh   : M=8192 N=1024 K=1536
  gemm_bt_bias<<<dim3((2 * H_) / BN, M_ / BM), 256, 0, stream>>>(
      A0, Wfhb, b_fh, gf, M_, 2 * H_, FS_);

  // recurrence: 64 sequential steps, ping-pong h buffers
  for (int t = 0; t < T_; t++) {
    const bf16_t* hin_b = (t & 1) ? h1b : h0b;
    const float*  hin_f = (t & 1) ? h1f : h0f;
    bf16_t* hout_b = (t & 1) ? h0b : h1b;
    float*  hout_f = (t & 1) ? h0f : h1f;
    gru_step<<<256, 64, 0, stream>>>(hin_b, hin_f, hout_b, hout_f,
                                     Whhb, b_hh, gi, gf, out, t);
  }

  // hT: step 63 (odd) wrote h0f
  hipMemcpyAsync(out + (size_t)M_ * H_, h0f, (size_t)B_ * H_ * 4,
                 hipMemcpyDeviceToDevice, stream);
}